// Round 8
// baseline (1738.510 us; speedup 1.0000x reference)
//
#include <hip/hip_runtime.h>
#include <hip/hip_bf16.h>

#define HIDDEN 128
#define NRAD 6

typedef __attribute__((ext_vector_type(8))) short  short8v;
typedef __attribute__((ext_vector_type(4))) float  f32x4;
typedef __attribute__((ext_vector_type(4))) int    int4v;

__device__ __forceinline__ float silu_f(float z) {
    return z / (1.0f + __expf(-z));
}
__device__ __forceinline__ short bf_hi(float v) {
    __hip_bfloat16 b = __float2bfloat16(v);
    return *reinterpret_cast<short*>(&b);
}

// ---------------------------------------------------------------------------
// Kernel A: per-type tables T1/T2 (fp32) + W3 in MFMA A-fragment layout (bf16).
//
// Numerics: rounds 1 (fp32) and 6 (3-term split-bf16) both measured absmax
// 0.0078125 — the harness comparison floors at bf16 granularity, and plain
// single-term bf16 MFMA adds only ~2e-3 (35x under the 0.052 threshold), so
// the hi/lo split was dropped. The A/B k-slot pairing was probed on-device
// in rounds 5/6: it is the IDENTITY (round-6 passed with identity packing),
// so the probe is retired.
//
//   T1[t][h] = lin_b[h] + sum_k lin_w[h][k]     * emb_w[t][k]
//   T2[t][h] =            sum_k lin_w[h][128+k] * emb_w[t][k]
//   W3F fragment pos = ((kk*8+f)*64 + lane)*8 + j  holds (bf16)
//       w = lin_w[f*16+(lane&15)][256 + kk*32 + (lane>>4)*8 + j]
// ---------------------------------------------------------------------------
__global__ void build_tables(const float* __restrict__ emb_w,
                             const float* __restrict__ lin_w,
                             const float* __restrict__ lin_b,
                             float* __restrict__ T1,
                             float* __restrict__ T2,
                             short* __restrict__ W3F,
                             int n_types)
{
    __shared__ float hv[HIDDEN];
    int b = blockIdx.x;
    int h = threadIdx.x;          // 0..127
    if (b < n_types) {
        hv[h] = emb_w[b * HIDDEN + h];
        __syncthreads();
        float a1 = lin_b[h];
        float a2 = 0.0f;
        const float* wrow = lin_w + (size_t)h * (3 * HIDDEN);
        #pragma unroll 8
        for (int k = 0; k < HIDDEN; ++k) {
            float e = hv[k];
            a1 = fmaf(wrow[k], e, a1);
            a2 = fmaf(wrow[HIDDEN + k], e, a2);
        }
        T1[b * HIDDEN + h] = a1;
        T2[b * HIDDEN + h] = a2;
    } else {
        int tb = b - n_types;                 // 0..31, 512 fragment slots each
        #pragma unroll
        for (int q = 0; q < 4; ++q) {
            int pos = tb * 512 + q * 128 + h; // 0..16383
            int j  = pos & 7;
            int l  = (pos >> 3) & 63;
            int f  = (pos >> 9) & 7;
            int kk = pos >> 12;
            int hh = f * 16 + (l & 15);
            int k  = kk * 32 + (l >> 4) * 8 + j;
            W3F[pos] = bf_hi(lin_w[(size_t)hh * (3 * HIDDEN) + 2 * HIDDEN + k]);
        }
    }
}

// ---------------------------------------------------------------------------
// Main edge kernel. One 16-edge MFMA tile per wave-iteration (register
// pressure kept < 128 VGPR — round-6's 2-tile hi/lo variant spilled ~2.5 GB
// of scratch traffic to HBM).
//   out[e][h] = silu( T1[x[i[e]]][h] + T2[x[j[e]]][h] + sum_c W3[h][c]*s[e][c] )
//   s[e][c] = silu(rbf[e] . rw[c] + rb[c]) computed per-lane in registers,
//   packed bf16 as the MFMA B operand (N = edge, lane eh owns edge, g4 owns
//   k-slots g4*8..g4*8+7 of each 32-wide kk block).
// ---------------------------------------------------------------------------
__global__ __launch_bounds__(512, 4)
void edge_kernel(const int*   __restrict__ x,
                 const float* __restrict__ rbf,
                 const int*   __restrict__ ei,
                 const int*   __restrict__ ej,
                 const float* __restrict__ rw,    // [128][6]
                 const float* __restrict__ rb,    // [128]
                 const float* __restrict__ T1,
                 const float* __restrict__ T2,
                 const short* __restrict__ W3F,   // bf16 A-fragments
                 float*       __restrict__ out,
                 int E)
{
    __shared__ short W3s[16384];                 // 32 KB

    // one-time stage, coalesced int4 (2048 units / 512 threads = 4 each)
    {
        const int4v* g = (const int4v*)W3F;
        int4v* s = (int4v*)W3s;
        #pragma unroll
        for (int q = 0; q < 4; ++q) s[q * 512 + threadIdx.x] = g[q * 512 + threadIdx.x];
    }
    __syncthreads();

    const int tid  = threadIdx.x;
    const int lane = tid & 63;
    const int wv   = tid >> 6;
    const int eh   = lane & 15;   // edge within tile (MFMA N / C-col)
    const int g4   = lane >> 4;   // k-slot group / C-row quad

    const int ntiles = (E + 15) >> 4;

    for (int tile = blockIdx.x * 8 + wv; tile < ntiles; tile += gridDim.x * 8) {
        const int e  = (tile << 4) + eh;
        const int ec = (e < E) ? e : (E - 1);

        // gather-index chains issued early (consumed in the epilogue)
        const int xi = x[ei[ec]];
        const int xj = x[ej[ec]];

        // per-lane rbf row (24 B)
        float rv[6];
        {
            const float2* p = (const float2*)(rbf + (size_t)ec * NRAD);
            float2 a0 = p[0], a1 = p[1], a2 = p[2];
            rv[0]=a0.x; rv[1]=a0.y; rv[2]=a1.x; rv[3]=a1.y; rv[4]=a2.x; rv[5]=a2.y;
        }

        // rbf hidden layer -> bf16 B-fragments, all in registers
        short8v B[4];
        #pragma unroll
        for (int kk = 0; kk < 4; ++kk) {
            const int c0 = kk * 32 + g4 * 8;
            float rwv[48];
            {
                const f32x4* p = (const f32x4*)(rw + c0 * NRAD);  // 192 B contiguous
                #pragma unroll
                for (int q = 0; q < 12; ++q) {
                    f32x4 v = p[q];
                    rwv[q*4+0] = v[0]; rwv[q*4+1] = v[1]; rwv[q*4+2] = v[2]; rwv[q*4+3] = v[3];
                }
            }
            float rbv[8];
            {
                const f32x4* p = (const f32x4*)(rb + c0);
                f32x4 v0 = p[0], v1 = p[1];
                rbv[0]=v0[0]; rbv[1]=v0[1]; rbv[2]=v0[2]; rbv[3]=v0[3];
                rbv[4]=v1[0]; rbv[5]=v1[1]; rbv[6]=v1[2]; rbv[7]=v1[3];
            }
            #pragma unroll
            for (int j = 0; j < 8; ++j) {
                float z = rbv[j];
                #pragma unroll
                for (int r = 0; r < NRAD; ++r)
                    z = fmaf(rwv[j * NRAD + r], rv[r], z);
                B[kk][j] = bf_hi(silu_f(z));
            }
        }

        // MFMA: acc[f] covers h = f*16 + g4*4 + reg for edge column eh
        f32x4 acc[8];
        #pragma unroll
        for (int f = 0; f < 8; ++f) acc[f] = (f32x4){0.f, 0.f, 0.f, 0.f};

        const short8v* Ap = (const short8v*)W3s;
        #pragma unroll
        for (int kk = 0; kk < 4; ++kk) {
            #pragma unroll
            for (int f = 0; f < 8; ++f) {
                short8v Ah = Ap[(kk * 8 + f) * 64 + lane];
                acc[f] = __builtin_amdgcn_mfma_f32_16x16x32_bf16(Ah, B[kk], acc[f], 0, 0, 0);
            }
        }

        // epilogue: + T1[x[i]] + T2[x[j]], silu, f32x4 stores
        const f32x4* t1p = (const f32x4*)(T1 + (size_t)xi * HIDDEN) + g4;
        const f32x4* t2p = (const f32x4*)(T2 + (size_t)xj * HIDDEN) + g4;
        if (e < E) {
            f32x4* op = (f32x4*)(out + (size_t)e * HIDDEN) + g4;
            #pragma unroll
            for (int f = 0; f < 8; ++f) {
                f32x4 v1 = t1p[f * 4];
                f32x4 v2 = t2p[f * 4];
                f32x4 a  = acc[f];
                f32x4 o;
                #pragma unroll
                for (int r = 0; r < 4; ++r)
                    o[r] = silu_f(a[r] + v1[r] + v2[r]);
                op[f * 4] = o;
            }
        }
    }
}

// ---------------------------------------------------------------------------
extern "C" void kernel_launch(void* const* d_in, const int* in_sizes, int n_in,
                              void* d_out, int out_size, void* d_ws, size_t ws_size,
                              hipStream_t stream)
{
    const int*   x         = (const int*)  d_in[0];
    const float* rbf       = (const float*)d_in[1];
    const int*   ei        = (const int*)  d_in[2];
    const int*   ej        = (const int*)  d_in[3];
    const float* emb_w     = (const float*)d_in[4];
    const float* lin_rbf_w = (const float*)d_in[5];
    const float* lin_rbf_b = (const float*)d_in[6];
    const float* lin_w     = (const float*)d_in[7];
    const float* lin_b     = (const float*)d_in[8];

    int E  = in_sizes[2];                 // edge count
    int NT = in_sizes[4] / HIDDEN;        // number of node types (95)

    // workspace: T1 | T2 | W3F (bf16 A-fragments, 32 KB)
    float* T1  = (float*)d_ws;
    float* T2  = T1 + (size_t)NT * HIDDEN;
    short* W3F = (short*)(T2 + (size_t)NT * HIDDEN);

    hipLaunchKernelGGL(build_tables, dim3(NT + 32), dim3(HIDDEN), 0, stream,
                       emb_w, lin_w, lin_b, T1, T2, W3F, NT);

    // 2 blocks/CU resident (VGPR-bound), grid exactly fills 256 CUs
    hipLaunchKernelGGL(edge_kernel, dim3(512), dim3(512), 0, stream,
                       x, rbf, ei, ej, lin_rbf_w, lin_rbf_b,
                       T1, T2, W3F, (float*)d_out, E);
}